// Round 12
// baseline (78.022 us; speedup 1.0000x reference)
//
#include <hip/hip_runtime.h>

// BPS pipeline v12: v11 math; stage_ang widened to 512 threads (8 waves/block,
// seg owns 24 rows) + LDS trimmed to 52.25KB -> 3 blocks/CU (24 waves/CU = 6/SIMD).
// d_out = f32[2L]: [0,L) = real(x*exp(i*ph)), [L,2L) = ph = unwrap(ang)/4.

#define LN   65536
#define PI_F 3.14159265358979323846f
#define TWO_PI_F 6.2831853071795864769f

#define CORR(dd) (((dd) < -PI_F) ? 1 : (((dd) > PI_F) ? -1 : 0))

// Stage 1: per block of 64 outputs. Thread (m = t&63, seg = t>>6 in 0..7) owns rows
// seg*24..seg*24+23 of the 192-row (64-halo) dist tile for column m.
// dist -> P1 (prefix along l) -> box1 = P1 diff -> Q (prefix of box1) -> mvg = Q diff.
__global__ __launch_bounds__(512) void v12_stage_ang(const float* __restrict__ xr,
                                                     const float* __restrict__ xi,
                                                     const float* __restrict__ temp,
                                                     float* __restrict__ ang_out) {
    __shared__ float P1[64 * 193];      // P1[m][li] (pad 193); reused as Q[m*131+j]
    __shared__ float xsr[192], xsi[192];// staged x halo tile
    __shared__ float tot[8][64];        // per-(seg,m) totals (reused pass1 -> pass2)
    __shared__ float s4v[64], c4v[64];

    const int t   = threadIdx.x;
    const int l0  = blockIdx.x * 64;
    const int m   = t & 63;
    const int seg = t >> 6;             // == wave id; uniform per wave

    // stage x tile (coalesced) + sin/cos tables
    if (t < 192) {
        int gl = l0 - 64 + t;
        bool ok = (unsigned)gl < (unsigned)LN;
        xsr[t] = ok ? xr[gl] : 0.0f;
        xsi[t] = ok ? xi[gl] : 0.0f;
    }
    if (t >= 448) {                     // distinct wave does the trig table
        int mm = t - 448;
        float a4 = (float)mm * (PI_F / 32.0f) - PI_F;   // 4*angles[mm]
        float s, c; sincosf(a4, &s, &c);
        s4v[mm] = s; c4v[mm] = c;
    }
    __syncthreads();

    // ---- Phase 1: dist (separable nearest-64QAM quantization) + register prefix ----
    {
        const float am = (float)m * (PI_F / 128.0f) - (PI_F * 0.25f);
        float sm, cm; sincosf(am, &sm, &cm);
        const float SQ = 6.4807406984078602f;   // sqrt(42)
        const float cq = cm * SQ, sq = sm * SQ;
        float pr[24];
        float p = 0.0f;
        #pragma unroll
        for (int i = 0; i < 24; ++i) {
            int li = seg * 24 + i;
            float a = xsr[li], b = xsi[li];     // LDS broadcast
            float tr = a * cq - b * sq;
            float ti = a * sq + b * cq;
            float rr = fminf(fmaxf(rintf(fmaf(tr, 0.5f, 3.5f)), 0.0f), 7.0f);
            float ri = fminf(fmaxf(rintf(fmaf(ti, 0.5f, 3.5f)), 0.0f), 7.0f);
            float dr = fmaf(-2.0f, rr, tr + 7.0f);
            float di = fmaf(-2.0f, ri, ti + 7.0f);
            float d = fmaf(dr, dr, di * di) * (1.0f / 42.0f);
            d = ((unsigned)(l0 - 64 + li) < (unsigned)LN) ? d : 0.0f;  // conv zero-pad
            p += d;
            pr[i] = p;
        }
        tot[seg][m] = p;
        __syncthreads();
        float off = 0.0f;
        #pragma unroll
        for (int s = 0; s < 7; ++s) if (s < seg) off += tot[s][m];
        #pragma unroll
        for (int i = 0; i < 24; ++i) P1[m * 193 + seg * 24 + i] = pr[i] + off;
    }
    __syncthreads();

    // ---- Phase 2: box1[j]=P1[63+j]-P1[j-2], j=0..128; register prefix -> Q ----
    const int j0 = seg * 17;
    const int jn = (seg < 7) ? 17 : 10;     // 7*17 + 10 = 129
    {
        float q[17];
        float p2 = 0.0f;
        #pragma unroll
        for (int i = 0; i < 17; ++i) {
            if (i < jn) {
                int j = j0 + i;
                float hi = P1[m * 193 + 63 + j];
                float lo = (j >= 2) ? P1[m * 193 + j - 2] : 0.0f;
                p2 += hi - lo;
                q[i] = p2;
            }
        }
        tot[seg][m] = p2;                   // safe: all pass-1 reads were pre-barrier
        __syncthreads();                    // also: all P1 reads done -> reuse as Q
        float off2 = 0.0f;
        #pragma unroll
        for (int s = 0; s < 7; ++s) if (s < seg) off2 += tot[s][m];
        float* Q = P1;                      // Q[m][j] at m*131 + j
        #pragma unroll
        for (int i = 0; i < 17; ++i) if (i < jn) Q[m * 131 + j0 + i] = q[i] + off2;
    }
    __syncthreads();

    // ---- Phase 3: mvg[r][mm] = Q[mm][r+65]-Q[mm][r]; normalize+softmin+atan2.
    //      8 lanes per output row, 8 m's per lane. ----
    {
        const float* Q = P1;
        const float T = temp[0];
        const int lane = t & 63;
        const int sub  = lane & 7;
        const int r    = (t >> 6) * 8 + (lane >> 3);   // 0..63
        const int mb   = sub * 8;

        float v[8];
        float rs = 0.0f, mn = 3.4e38f;
        #pragma unroll
        for (int i = 0; i < 8; ++i) {
            int mm = mb + i;
            float vv = Q[mm * 131 + r + 65] - Q[mm * 131 + r];
            v[i] = vv; rs += vv; mn = fminf(mn, vv);
        }
        rs += __shfl_xor(rs, 1, 64); rs += __shfl_xor(rs, 2, 64); rs += __shfl_xor(rs, 4, 64);
        mn = fminf(mn, __shfl_xor(mn, 1, 64));
        mn = fminf(mn, __shfl_xor(mn, 2, 64));
        mn = fminf(mn, __shfl_xor(mn, 4, 64));

        // softmax(-mvg_norm/T) weights exp((mn-v)/(rs*T)); denominator cancels in atan2
        float inv = 1.0f / (rs * T);
        float ss = 0.0f, sc = 0.0f;
        #pragma unroll
        for (int i = 0; i < 8; ++i) {
            int mm = mb + i;
            float e = __expf((mn - v[i]) * inv);
            ss = fmaf(e, s4v[mm], ss);
            sc = fmaf(e, c4v[mm], sc);
        }
        ss += __shfl_xor(ss, 1, 64); ss += __shfl_xor(ss, 2, 64); ss += __shfl_xor(ss, 4, 64);
        sc += __shfl_xor(sc, 1, 64); sc += __shfl_xor(sc, 2, 64); sc += __shfl_xor(sc, 4, 64);
        if (sub == 0) ang_out[l0 + r] = atan2f(ss, sc);
    }
}

// Stage 2: coalesced block-local correction scan (64 blocks x 256 thr x 4 elem).
__global__ __launch_bounds__(256) void v12_scan_local(const float* __restrict__ ang,
                                                      int* __restrict__ klocal,
                                                      int* __restrict__ bsum) {
    __shared__ int wtot[4];
    const int t = threadIdx.x;
    const int b = blockIdx.x;
    const int e = b * 256 + t;
    const int i4 = e * 4;

    float4 a = *(const float4*)(ang + i4);
    float prev = (i4 == 0) ? 0.0f : ang[i4 - 1];

    int s0 = CORR(a.x - prev);
    int s1 = CORR(a.y - a.x);
    int s2 = CORR(a.z - a.y);
    int s3 = CORR(a.w - a.z);
    int k0 = s0, k1 = k0 + s1, k2 = k1 + s2, k3 = k2 + s3;

    const int lane = t & 63, wv = t >> 6;
    int scan = k3;
    #pragma unroll
    for (int off = 1; off < 64; off <<= 1) {
        int v = __shfl_up(scan, off, 64);
        if (lane >= off) scan += v;
    }
    if (lane == 63) wtot[wv] = scan;
    __syncthreads();
    int woff = 0;
    #pragma unroll
    for (int j = 0; j < 3; ++j) if (j < wv) woff += wtot[j];
    const int excl = woff + scan - k3;

    ((int4*)klocal)[e] = make_int4(excl + k0, excl + k1, excl + k2, excl + k3);
    if (t == 255) bsum[b] = woff + scan;
}

// Stage 3: k = klocal + chunk offset; ph=(ang+2pi k)/4;
// d_out: [0,L) = real(x*exp(i*ph)), [L,2L) = ph.
__global__ __launch_bounds__(512) void v12_stage_out(const float* __restrict__ xr,
                                                     const float* __restrict__ xi,
                                                     const float* __restrict__ ang,
                                                     const int* __restrict__ klocal,
                                                     const int* __restrict__ bsum,
                                                     float* __restrict__ out_base) {
    __shared__ int s_boff;
    const int t = threadIdx.x;
    const int b = blockIdx.x;
    const int chunk = b >> 1;

    if (t < 64) {
        int v = (t < chunk) ? bsum[t] : 0;
        #pragma unroll
        for (int off = 1; off < 64; off <<= 1) v += __shfl_xor(v, off, 64);
        if (t == 0) s_boff = v;
    }
    __syncthreads();

    const int l = b * 512 + t;
    float ph = (ang[l] + TWO_PI_F * (float)(klocal[l] + s_boff)) * 0.25f;
    float s, c; sincosf(ph, &s, &c);
    float a = xr[l], bb = xi[l];
    out_base[l]      = a * c - bb * s;   // real(out)
    out_base[LN + l] = ph;               // ph channel
}

extern "C" void kernel_launch(void* const* d_in, const int* in_sizes, int n_in,
                              void* d_out, int out_size, void* d_ws, size_t ws_size,
                              hipStream_t stream) {
    (void)in_sizes; (void)n_in; (void)out_size; (void)ws_size;
    const float* xr   = (const float*)d_in[0];
    const float* xi   = (const float*)d_in[1];
    const float* temp = (const float*)d_in[5];

    float* ang    = (float*)d_ws;                                  // L f32
    int*   klocal = (int*)((char*)d_ws + LN * sizeof(float));      // L i32
    int*   bsum   = (int*)((char*)d_ws + 2 * LN * sizeof(float));  // 64 i32

    v12_stage_ang <<<LN / 64, 512, 0, stream>>>(xr, xi, temp, ang);
    v12_scan_local<<<64, 256, 0, stream>>>(ang, klocal, bsum);
    v12_stage_out <<<LN / 512, 512, 0, stream>>>(xr, xi, ang, klocal, bsum, (float*)d_out);
}